// Round 2
// baseline (450.349 us; speedup 1.0000x reference)
//
#include <hip/hip_runtime.h>

#define T_STEPS 1024
// H = F = 6, 4H = 24 gate rows, PyTorch order: i[0:6) f[6:12) g[12:18) o[18:24)
//
// Lane layout: 32 lanes per batch element (2 elements per wave, 8 per 256-block).
// Within a 32-lane half:
//   lanes 0..5   : L0, gates (i,f) for column j = lane      -- owns c0_j, produces h0_j
//   lanes 8..13  : L0, gates (g,o) for column j = lane-8
//   lanes 16..21 : L1, gates (i,f) for column j  (staggered: computes step t-1)
//   lanes 24..29 : L1, gates (g,o)
//   lanes 6,7,14,15,22,23,30,31: duplicate j=5, results unused.
// vs R1: per-lane work halves (24 FMAs, 6 trans) and wave count doubles
// (2048 waves = 2/SIMD) so stall windows of one wave are filled by the other.

__device__ __forceinline__ float vexp2(float x) { return __builtin_amdgcn_exp2f(x); }
__device__ __forceinline__ float vrcp(float x)  { return __builtin_amdgcn_rcpf(x); }
// sigmoid(x) = rcp(1 + 2^(-x*log2e))
__device__ __forceinline__ float sigm(float x) {
    return vrcp(1.0f + vexp2(x * -1.44269504088896340736f));
}
// tanh(x) = 2*sigmoid(2x) - 1
__device__ __forceinline__ float tanh_f(float x) {
    return fmaf(2.0f, sigm(2.0f * x), -1.0f);
}

// ds_swizzle BitMode (offset = xor<<10 | or<<5 | and): src = ((lane&and)|or)^xor,
// applied independently within each 32-lane half.
#define SWZ_BCAST(v, s) \
    __int_as_float(__builtin_amdgcn_ds_swizzle(__float_as_int(v), ((s) << 5)))
#define SWZ_XOR8(v) \
    __int_as_float(__builtin_amdgcn_ds_swizzle(__float_as_int(v), ((8 << 10) | 0x1F)))

__global__ __launch_bounds__(256) void lstm2_kernel(
    const float* __restrict__ x,
    const float* __restrict__ wih0, const float* __restrict__ whh0,
    const float* __restrict__ bih0, const float* __restrict__ bhh0,
    const float* __restrict__ wih1, const float* __restrict__ whh1,
    const float* __restrict__ bih1, const float* __restrict__ bhh1,
    float* __restrict__ out, int Btot)
{
    const int tid = threadIdx.x;
    const int l   = tid & 31;
    const int b   = blockIdx.x * 8 + (tid >> 5);
    if (b >= Btot) return;             // uniform per 32-lane group

    const bool isL1 = (l & 16) != 0;
    const bool isGO = (l & 8) != 0;
    int j = l & 7; if (j > 5) j = 5;   // dup lanes clamp to j=5

    const int rA = isGO ? (12 + j) : j;        // g-row (GO) or i-row (IF)
    const int rB = isGO ? (18 + j) : (6 + j);  // o-row (GO) or f-row (IF)

    // A-operand weights multiply the h0 broadcast (recurrent h for L0, input for L1);
    // B-operand weights multiply x (L0) or the h1 broadcast (L1).
    const float* wa  = isL1 ? wih1 : whh0;
    const float* wb  = isL1 ? whh1 : wih0;
    const float* bip = isL1 ? bih1 : bih0;
    const float* bhp = isL1 ? bhh1 : bhh0;

    float waA[6], waB[6], wbA[6], wbB[6];
#pragma unroll
    for (int k = 0; k < 6; ++k) {
        waA[k] = wa[rA * 6 + k]; waB[k] = wa[rB * 6 + k];
        wbA[k] = wb[rA * 6 + k]; wbB[k] = wb[rB * 6 + k];
    }
    const float bA = bip[rA] + bhp[rA];
    const float bB = bip[rB] + bhp[rB];

    float h0b[6], h1b[6];
#pragma unroll
    for (int k = 0; k < 6; ++k) { h0b[k] = 0.0f; h1b[k] = 0.0f; }
    float c = 0.0f;

    const float* px = x + (size_t)b * (T_STEPS * 6);
    float* ps = out + (size_t)b * (T_STEPS * 6) + (l - 16);
    const bool lstore = (l >= 16) && (l < 22);   // L1 IF lanes store h1_j

    auto loadx = [&](int t, float v[6]) {
        const float2* p2 = reinterpret_cast<const float2*>(px + (size_t)t * 6);
        float2 a = p2[0], b2 = p2[1], c2 = p2[2];
        v[0] = a.x; v[1] = a.y; v[2] = b2.x; v[3] = b2.y; v[4] = c2.x; v[5] = c2.y;
    };

    // At iter K: L0 lanes compute step K (B-in = x(K), A-in = h0b = h0(K-1));
    // L1 lanes compute step K-1 (B-in = h1b = h1(K-2), A-in = h0b = h0(K-1)).
    // x(K+3) prefetched before the step so global loads overlap ~3 iterations.
#define ITER(K, CUR, PF)                                                        \
    {                                                                           \
        int tn_ = (K) + 3; if (tn_ > T_STEPS - 1) tn_ = T_STEPS - 1;            \
        loadx(tn_, PF);                                                         \
        float gA = bA, gB = bB, hA = 0.0f, hB = 0.0f;                           \
        _Pragma("unroll")                                                       \
        for (int q = 0; q < 6; ++q) {                                           \
            float bin = isL1 ? h1b[q] : CUR[q];                                 \
            gA = fmaf(wbA[q], bin, gA);  gB = fmaf(wbB[q], bin, gB);            \
            hA = fmaf(waA[q], h0b[q], hA); hB = fmaf(waB[q], h0b[q], hB);       \
        }                                                                       \
        float sA = gA + hA, sB = gB + hB;                                       \
        float preA = isGO ? 2.0f * sA : sA;                                     \
        float tAct = sigm(preA);                                                \
        float aA = isGO ? fmaf(2.0f, tAct, -1.0f) : tAct; /* sig(i)|tanh(g) */  \
        float aB = sigm(sB);                              /* sig(f)|sig(o) */   \
        float eA = SWZ_XOR8(aA);   /* on IF lanes: tanh(g) from partner */      \
        float eB = SWZ_XOR8(aB);   /* on IF lanes: sig(o) from partner  */      \
        c = fmaf(aB, c, aA * eA);                 /* valid on IF lanes */       \
        float hv = eB * tanh_f(c);                /* valid on IF lanes */       \
        if ((K) >= 1 && lstore) ps[(size_t)((K) - 1) * 6] = hv;                 \
        h0b[0] = SWZ_BCAST(hv, 0);  h0b[1] = SWZ_BCAST(hv, 1);                  \
        h0b[2] = SWZ_BCAST(hv, 2);  h0b[3] = SWZ_BCAST(hv, 3);                  \
        h0b[4] = SWZ_BCAST(hv, 4);  h0b[5] = SWZ_BCAST(hv, 5);                  \
        h1b[0] = SWZ_BCAST(hv, 16); h1b[1] = SWZ_BCAST(hv, 17);                 \
        h1b[2] = SWZ_BCAST(hv, 18); h1b[3] = SWZ_BCAST(hv, 19);                 \
        h1b[4] = SWZ_BCAST(hv, 20); h1b[5] = SWZ_BCAST(hv, 21);                 \
    }

    float xA[6], xB[6], xC[6], xD[6];
    loadx(0, xA); loadx(1, xB); loadx(2, xC);

    // Peel K=0: L0 computes step 0; L1 lanes compute garbage (biases), reset after.
    ITER(0, xA, xD);
    if (isL1) c = 0.0f;
#pragma unroll
    for (int k = 0; k < 6; ++k) h1b[k] = 0.0f;

    // Main: K = 1..1024 (256 exact quads). At K = T the L0 lanes compute a garbage
    // step T (clamped x) whose output is never consumed; L1 produces row T-1.
    for (int k = 1; k <= T_STEPS; k += 4) {
        ITER(k,     xB, xA);
        ITER(k + 1, xC, xB);
        ITER(k + 2, xD, xC);
        ITER(k + 3, xA, xD);
    }
#undef ITER
}

extern "C" void kernel_launch(void* const* d_in, const int* in_sizes, int n_in,
                              void* d_out, int out_size, void* d_ws, size_t ws_size,
                              hipStream_t stream)
{
    const float* x    = (const float*)d_in[0];
    const float* wih0 = (const float*)d_in[1];
    const float* whh0 = (const float*)d_in[2];
    const float* bih0 = (const float*)d_in[3];
    const float* bhh0 = (const float*)d_in[4];
    const float* wih1 = (const float*)d_in[5];
    const float* whh1 = (const float*)d_in[6];
    const float* bih1 = (const float*)d_in[7];
    const float* bhh1 = (const float*)d_in[8];
    float* out = (float*)d_out;

    const int Btot   = in_sizes[0] / (T_STEPS * 6);
    const int blocks = (Btot + 7) / 8;     // 8 elements per 256-thread block
    hipLaunchKernelGGL(lstm2_kernel, dim3(blocks), dim3(256), 0, stream,
                       x, wih0, whh0, bih0, bhh0, wih1, whh1, bih1, bhh1, out, Btot);
}